// Round 5
// baseline (43.244 us; speedup 1.0000x reference)
//
#include <hip/hip_runtime.h>

// Problem constants: B=8, N=1024, F=128, H=4, K=32, TAU=1

// ---------------------------------------------------------------------------
// Prep: transpose keys into KTQ[fq][hk] (float4 = K[hk][4fq..4fq+3]).
// 4096 float4s. Makes phase-1 key reads coalesced (lane = hk).
// ---------------------------------------------------------------------------
__global__ __launch_bounds__(256) void mempool_prep(
    const float* __restrict__ keys, float* __restrict__ ktq) {
  const int i = blockIdx.x * 256 + threadIdx.x;  // 0..4095
  const int fq = i >> 7;
  const int hk = i & 127;
  reinterpret_cast<float4*>(ktq)[i] =
      reinterpret_cast<const float4*>(keys)[hk * 32 + fq];
}

// ---------------------------------------------------------------------------
// Phase 1: S[bn][k] for all 8192 points.
// 1024 blocks x 256 threads, 8 points per block. Thread = (hk=t&127,
// half=t>>7) covers feature half [half*64, half*64+64) for all 8 points.
// Keys stream from global ktq: kq[j*128] is 1 KB contiguous per wave
// (L1/L2-hot, 64 KB total). x loads are wave-uniform -> broadcast.
// No key LDS mirror -> only 5 KB LDS -> high occupancy (4 waves/SIMD).
// Epilogue (2 barriers): half-combine -> Student-t + per-head 32-lane shfl
// normalize -> conv-combine + softmax over k (32-lane shfl) -> S_out.
// ---------------------------------------------------------------------------
#define P1_PTS 8

__global__ __launch_bounds__(256, 4) void mempool_phase1(
    const float* __restrict__ x, const float* __restrict__ ktq,
    const float* __restrict__ conv_w, float* __restrict__ S_out) {
  const int t = threadIdx.x;
  const int hk = t & 127;
  const int half = t >> 7;

  __shared__ float accs[P1_PTS][2][128];  // 8 KB
  __shared__ float cwsn[P1_PTS][4][32];   // 4 KB

  const int bn0 = blockIdx.x * P1_PTS;
  const float4* xq =
      reinterpret_cast<const float4*>(x) + (size_t)bn0 * 32 + half * 16;
  const float4* kq =
      reinterpret_cast<const float4*>(ktq) + (size_t)half * 16 * 128 + hk;

  float acc[P1_PTS];
#pragma unroll
  for (int p = 0; p < P1_PTS; ++p) acc[p] = 0.f;

#pragma unroll 4
  for (int j = 0; j < 16; ++j) {
    const float4 kv = kq[j * 128];  // coalesced: lane=hk contiguous
#pragma unroll
    for (int p = 0; p < P1_PTS; ++p) {
      const float4 xv = xq[p * 32 + j];  // wave-uniform -> broadcast
      acc[p] += fabsf(kv.x - xv.x) + fabsf(kv.y - xv.y) +
                fabsf(kv.z - xv.z) + fabsf(kv.w - xv.w);
    }
  }

#pragma unroll
  for (int p = 0; p < P1_PTS; ++p) accs[p][half][hk] = acc[p];
  __syncthreads();

  // Half-combine + Student-t + per-head normalize.
  // 1024 (p,hk) pairs / 256 threads = 4 each; 32-lane groups share (p,h).
  const float cw = conv_w[hk >> 5];
#pragma unroll
  for (int i = 0; i < 4; ++i) {
    const int p = half * 4 + i;
    const float d = accs[p][0][hk] + accs[p][1][hk];
    const float tv = __builtin_amdgcn_rcpf(1.f + d * d);  // Student-t, tau=1
    float hs = tv;
#pragma unroll
    for (int m = 1; m < 32; m <<= 1) hs += __shfl_xor(hs, m);
    cwsn[p][hk >> 5][hk & 31] = cw * tv * __builtin_amdgcn_rcpf(hs);
  }
  __syncthreads();

  // Conv-combine over heads + softmax over k: thread = (p = t>>5, k = t&31).
  {
    const int p = t >> 5;
    const int k = t & 31;
    float sc = cwsn[p][0][k] + cwsn[p][1][k] + cwsn[p][2][k] + cwsn[p][3][k];
    float mx = sc;
#pragma unroll
    for (int m = 1; m < 32; m <<= 1) mx = fmaxf(mx, __shfl_xor(mx, m));
    const float e = __expf(sc - mx);
    float se = e;
#pragma unroll
    for (int m = 1; m < 32; m <<= 1) se += __shfl_xor(se, m);
    S_out[(size_t)(bn0 + p) * 32 + k] = e * __builtin_amdgcn_rcpf(se);
  }
}

// ---------------------------------------------------------------------------
// Phase 2a: partial pooled. Block = (b, chunk c of 32 points); 256 threads =
// (k = t&31, fs = t>>5). x read exactly once across all blocks.
// part[b][c][k][f] = sum_{n in chunk} S[b][n][k] * x[b][n][f]
// ---------------------------------------------------------------------------
#define CHUNKS 32
#define CHUNK_N 32

__global__ __launch_bounds__(256) void mempool_pool(
    const float* __restrict__ x, const float* __restrict__ S,
    float* __restrict__ part) {
  const int b = blockIdx.x >> 5;
  const int c = blockIdx.x & 31;
  const int t = threadIdx.x;
  const int k = t & 31;
  const int fs = t >> 5;  // 0..7
  const int n0 = c * CHUNK_N;

  const float4* x4 = reinterpret_cast<const float4*>(x) +
                     ((size_t)b * 1024 + n0) * 32 + fs * 4;
  const float* Sb = S + ((size_t)b * 1024 + n0) * 32 + k;

  float4 a0 = {0, 0, 0, 0}, a1 = {0, 0, 0, 0}, a2 = {0, 0, 0, 0},
         a3 = {0, 0, 0, 0};
#pragma unroll 4
  for (int n = 0; n < CHUNK_N; ++n) {
    const float s = Sb[n * 32];
    const float4 v0 = x4[n * 32 + 0];
    const float4 v1 = x4[n * 32 + 1];
    const float4 v2 = x4[n * 32 + 2];
    const float4 v3 = x4[n * 32 + 3];
    a0.x += s * v0.x; a0.y += s * v0.y; a0.z += s * v0.z; a0.w += s * v0.w;
    a1.x += s * v1.x; a1.y += s * v1.y; a1.z += s * v1.z; a1.w += s * v1.w;
    a2.x += s * v2.x; a2.y += s * v2.y; a2.z += s * v2.z; a2.w += s * v2.w;
    a3.x += s * v3.x; a3.y += s * v3.y; a3.z += s * v3.z; a3.w += s * v3.w;
  }

  float4* p4 = reinterpret_cast<float4*>(part) +
               (((size_t)(b * CHUNKS + c) * 32 + k) * 32 + fs * 4);
  p4[0] = a0;
  p4[1] = a1;
  p4[2] = a2;
  p4[3] = a3;
}

// ---------------------------------------------------------------------------
// Phase 2b: finalize. Block = (b,k), 128 threads.
// pooled[f] = sum_c part[b][c][k][f]; out = leaky(pooled . lin_w[fo])
// ---------------------------------------------------------------------------
__global__ __launch_bounds__(128) void mempool_out(
    const float* __restrict__ part, const float* __restrict__ lin_w,
    float* __restrict__ out) {
  const int b = blockIdx.x >> 5;
  const int k = blockIdx.x & 31;
  const int t = threadIdx.x;  // 0..127

  __shared__ float pooled[128];
  const float* pp = part + (((size_t)b * CHUNKS) * 32 + k) * 128 + t;
  float pf = 0.f;
#pragma unroll
  for (int c = 0; c < CHUNKS; ++c) pf += pp[(size_t)c * 32 * 128];
  pooled[t] = pf;
  __syncthreads();

  const float4* w4 = reinterpret_cast<const float4*>(lin_w) + t * 32;
  const float4* pl4 = reinterpret_cast<const float4*>(pooled);
  float o = 0.f;
#pragma unroll
  for (int j = 0; j < 32; ++j) {
    const float4 w = w4[j];
    const float4 p = pl4[j];
    o += w.x * p.x + w.y * p.y + w.z * p.z + w.w * p.w;
  }
  o = (o >= 0.f) ? o : 0.01f * o;
  out[(size_t)(b * 32 + k) * 128 + t] = o;
}

// ---------------------------------------------------------------------------
// Fallbacks (no workspace): round-1 structure (known-good).
// ---------------------------------------------------------------------------
__global__ __launch_bounds__(256) void mempool_phase1_fb(
    const float* __restrict__ x, const float* __restrict__ keys,
    const float* __restrict__ conv_w, float* __restrict__ S_out) {
  const int t = threadIdx.x;
  const int hk = t & 127;
  const int half = t >> 7;

  const float4* kq = reinterpret_cast<const float4*>(keys) + hk * 32 + half * 16;
  const float cw = conv_w[(t >> 5) & 3];

  __shared__ float lds_half[128];
  __shared__ float lds_ws[128];

  const int base = blockIdx.x * 8;
  for (int p = 0; p < 8; ++p) {
    const int bn = base + p;
    const float4* xq = reinterpret_cast<const float4*>(x) + bn * 32 + half * 16;
    float a0 = 0.f;
#pragma unroll
    for (int j = 0; j < 16; ++j) {
      const float4 kv = kq[j];
      const float4 xv = xq[j];
      a0 += fabsf(kv.x - xv.x) + fabsf(kv.y - xv.y) + fabsf(kv.z - xv.z) +
            fabsf(kv.w - xv.w);
    }
    if (t >= 128) lds_half[hk] = a0;
    __syncthreads();
    if (t < 128) {
      const float d = a0 + lds_half[hk];
      const float tv = 1.0f / (1.0f + d * d);
      float hs = tv;
#pragma unroll
      for (int m = 1; m < 32; m <<= 1) hs += __shfl_xor(hs, m);
      lds_ws[hk] = cw * tv / hs;
    }
    __syncthreads();
    if (t < 32) {
      float sc = lds_ws[t] + lds_ws[32 + t] + lds_ws[64 + t] + lds_ws[96 + t];
      float mx = sc;
#pragma unroll
      for (int m = 1; m < 32; m <<= 1) mx = fmaxf(mx, __shfl_xor(mx, m));
      const float e = __expf(sc - mx);
      float se = e;
#pragma unroll
      for (int m = 1; m < 32; m <<= 1) se += __shfl_xor(se, m);
      S_out[bn * 32 + t] = e / se;
    }
    __syncthreads();
  }
}

__global__ __launch_bounds__(256) void mempool_phase2_fb(
    const float* __restrict__ x, const float* __restrict__ S,
    const float* __restrict__ lin_w, float* __restrict__ out) {
  const int b = blockIdx.x >> 5;
  const int k = blockIdx.x & 31;
  const int t = threadIdx.x;
  const int fq = t & 31;
  const int seg = t >> 5;

  const float4* xq = reinterpret_cast<const float4*>(x) + (size_t)b * 1024 * 32;
  const float* Sb = S + (size_t)b * 1024 * 32 + k;

  float4 acc = {0.f, 0.f, 0.f, 0.f};
  const int n0 = seg * 128;
#pragma unroll 4
  for (int n = n0; n < n0 + 128; ++n) {
    const float sv = Sb[(size_t)n * 32];
    const float4 xv = xq[n * 32 + fq];
    acc.x += sv * xv.x;
    acc.y += sv * xv.y;
    acc.z += sv * xv.z;
    acc.w += sv * xv.w;
  }

  __shared__ float4 red[8][32];
  red[seg][fq] = acc;
  __syncthreads();

  __shared__ float4 pooled4[32];
  if (t < 32) {
    float4 a = red[0][t];
#pragma unroll
    for (int ss = 1; ss < 8; ++ss) {
      const float4 r = red[ss][t];
      a.x += r.x; a.y += r.y; a.z += r.z; a.w += r.w;
    }
    pooled4[t] = a;
  }
  __syncthreads();

  if (t < 128) {
    const float4* wq = reinterpret_cast<const float4*>(lin_w) + t * 32;
    float o = 0.f;
#pragma unroll
    for (int j = 0; j < 32; ++j) {
      const float4 w = wq[j];
      const float4 p = pooled4[j];
      o += w.x * p.x + w.y * p.y + w.z * p.z + w.w * p.w;
    }
    o = (o >= 0.f) ? o : 0.01f * o;
    out[(size_t)(b * 32 + k) * 128 + t] = o;
  }
}

extern "C" void kernel_launch(void* const* d_in, const int* in_sizes, int n_in,
                              void* d_out, int out_size, void* d_ws, size_t ws_size,
                              hipStream_t stream) {
  const float* x = (const float*)d_in[0];       // [8,1024,128]
  const float* keys = (const float*)d_in[1];    // [4,32,128]
  const float* conv_w = (const float*)d_in[2];  // [4]
  const float* lin_w = (const float*)d_in[3];   // [128,128]

  float* out = (float*)d_out;            // [8,32,128]
  float* S_out = (float*)d_out + 32768;  // [8,1024,32]

  const size_t ktq_floats = 128 * 128;                       // 64 KB
  const size_t part_floats = (size_t)8 * CHUNKS * 32 * 128;  // 4 MB
  const size_t need = (ktq_floats + part_floats) * sizeof(float);

  if (ws_size >= need) {
    float* ktq = (float*)d_ws;
    float* part = (float*)d_ws + ktq_floats;
    mempool_prep<<<16, 256, 0, stream>>>(keys, ktq);
    mempool_phase1<<<8192 / P1_PTS, 256, 0, stream>>>(x, ktq, conv_w, S_out);
    mempool_pool<<<8 * CHUNKS, 256, 0, stream>>>(x, S_out, part);
    mempool_out<<<8 * 32, 128, 0, stream>>>(part, lin_w, out);
  } else {
    mempool_phase1_fb<<<1024, 256, 0, stream>>>(x, keys, conv_w, S_out);
    mempool_phase2_fb<<<8 * 32, 256, 0, stream>>>(x, S_out, lin_w, out);
  }
}

// Round 6
// 34.055 us; speedup vs baseline: 1.2699x; 1.2699x over previous
//
#include <hip/hip_runtime.h>

// Problem constants: B=8, N=1024, F=128, H=4, K=32, TAU=1

// ---------------------------------------------------------------------------
// Prep: transpose keys into KTQ[fq][hk] (float4 = K[hk][4fq..4fq+3]).
// Makes phase-1 key reads coalesced (lane = hk).
// ---------------------------------------------------------------------------
__global__ __launch_bounds__(256) void mempool_prep(
    const float* __restrict__ keys, float* __restrict__ ktq) {
  const int i = blockIdx.x * 256 + threadIdx.x;  // 0..4095
  const int fq = i >> 7;
  const int hk = i & 127;
  reinterpret_cast<float4*>(ktq)[i] =
      reinterpret_cast<const float4*>(keys)[hk * 32 + fq];
}

// ---------------------------------------------------------------------------
// Phase 1: S[bn][k] for all 8192 points.
// 1024 blocks x 256 threads, 8 points/block. Thread = (hk=t&127, half=t>>7)
// covers feature half [half*64 .. half*64+64) of all 8 points.
// KEY CHANGE vs r4: x slice (4 KB) is LDS-staged with ONE coalesced VMEM
// load per thread; inner-loop x reads are uniform ds_read_b128 (broadcast,
// LDS pipe) instead of 128 wave-uniform VMEM loads. VMEM inst/thread:
// 144 -> 17, eliminating the VMEM address-processing bottleneck.
// Keys stream from global ktq, coalesced 1 KB/wave (L2-resident, 64 KB).
// ---------------------------------------------------------------------------
#define P1_PTS 8

__global__ __launch_bounds__(256, 4) void mempool_phase1(
    const float* __restrict__ x, const float* __restrict__ ktq,
    const float* __restrict__ conv_w, float* __restrict__ S_out) {
  const int t = threadIdx.x;
  const int hk = t & 127;
  const int half = t >> 7;

  __shared__ float4 xl[P1_PTS * 32];      // [p][fq], 4 KB
  __shared__ float accs[P1_PTS][2][128];  // 8 KB
  __shared__ float cwsn[P1_PTS][4][32];   // 4 KB

  const int bn0 = blockIdx.x * P1_PTS;

  // Stage x: 256 float4 = 1 per thread, fully coalesced.
  xl[t] = reinterpret_cast<const float4*>(x)[(size_t)bn0 * 32 + t];
  __syncthreads();

  const float4* kq =
      reinterpret_cast<const float4*>(ktq) + (size_t)half * 16 * 128 + hk;

  float acc[P1_PTS];
#pragma unroll
  for (int p = 0; p < P1_PTS; ++p) acc[p] = 0.f;

#pragma unroll 4
  for (int j = 0; j < 16; ++j) {
    const float4 kv = kq[j * 128];  // coalesced global: lane=hk contiguous
    const int fq = half * 16 + j;
#pragma unroll
    for (int p = 0; p < P1_PTS; ++p) {
      const float4 xv = xl[p * 32 + fq];  // uniform ds_read -> broadcast
      acc[p] += fabsf(kv.x - xv.x) + fabsf(kv.y - xv.y) +
                fabsf(kv.z - xv.z) + fabsf(kv.w - xv.w);
    }
  }

#pragma unroll
  for (int p = 0; p < P1_PTS; ++p) accs[p][half][hk] = acc[p];
  __syncthreads();

  // Half-combine + Student-t + per-head normalize.
  // 1024 (p,hk) pairs / 256 threads = 4 each; 32-lane groups share (p,h).
  const float cw = conv_w[hk >> 5];
#pragma unroll
  for (int i = 0; i < 4; ++i) {
    const int p = half * 4 + i;
    const float d = accs[p][0][hk] + accs[p][1][hk];
    const float tv = __builtin_amdgcn_rcpf(1.f + d * d);  // Student-t, tau=1
    float hs = tv;
#pragma unroll
    for (int m = 1; m < 32; m <<= 1) hs += __shfl_xor(hs, m);
    cwsn[p][hk >> 5][hk & 31] = cw * tv * __builtin_amdgcn_rcpf(hs);
  }
  __syncthreads();

  // Conv-combine over heads + softmax over k: thread = (p = t>>5, k = t&31).
  {
    const int p = t >> 5;
    const int k = t & 31;
    float sc = cwsn[p][0][k] + cwsn[p][1][k] + cwsn[p][2][k] + cwsn[p][3][k];
    float mx = sc;
#pragma unroll
    for (int m = 1; m < 32; m <<= 1) mx = fmaxf(mx, __shfl_xor(mx, m));
    const float e = __expf(sc - mx);
    float se = e;
#pragma unroll
    for (int m = 1; m < 32; m <<= 1) se += __shfl_xor(se, m);
    S_out[(size_t)(bn0 + p) * 32 + k] = e * __builtin_amdgcn_rcpf(se);
  }
}

// ---------------------------------------------------------------------------
// Phase 2a: partial pooled. Block = (b, chunk c of 32 points); 256 threads =
// (k = t&31, fs = t>>5). x-chunk (16 KB) and S-chunk (4 KB) LDS-staged with
// coalesced loads; inner loop reads are 2-way/broadcast LDS (free).
// part[b][c][k][f] = sum_{n in chunk} S[b][n][k] * x[b][n][f]
// ---------------------------------------------------------------------------
#define CHUNKS 32
#define CHUNK_N 32

__global__ __launch_bounds__(256) void mempool_pool(
    const float* __restrict__ x, const float* __restrict__ S,
    float* __restrict__ part) {
  const int b = blockIdx.x >> 5;
  const int c = blockIdx.x & 31;
  const int t = threadIdx.x;
  const int k = t & 31;
  const int fs = t >> 5;  // 0..7
  const int n0 = c * CHUNK_N;

  __shared__ float4 xl[CHUNK_N * 32];  // [n][fq], 16 KB
  __shared__ float sl[CHUNK_N * 32];   // [n][k],   4 KB

  {  // stage x: 1024 float4 / 256 thr = 4 each, coalesced
    const float4* xg =
        reinterpret_cast<const float4*>(x) + ((size_t)b * 1024 + n0) * 32;
#pragma unroll
    for (int i = 0; i < 4; ++i) xl[t + i * 256] = xg[t + i * 256];
    // stage S: 1024 floats = 256 float4, coalesced
    reinterpret_cast<float4*>(sl)[t] =
        reinterpret_cast<const float4*>(S + ((size_t)b * 1024 + n0) * 32)[t];
  }
  __syncthreads();

  float4 a0 = {0, 0, 0, 0}, a1 = {0, 0, 0, 0}, a2 = {0, 0, 0, 0},
         a3 = {0, 0, 0, 0};
#pragma unroll 4
  for (int n = 0; n < CHUNK_N; ++n) {
    const float s = sl[n * 32 + k];
    const float4 v0 = xl[n * 32 + fs * 4 + 0];
    const float4 v1 = xl[n * 32 + fs * 4 + 1];
    const float4 v2 = xl[n * 32 + fs * 4 + 2];
    const float4 v3 = xl[n * 32 + fs * 4 + 3];
    a0.x += s * v0.x; a0.y += s * v0.y; a0.z += s * v0.z; a0.w += s * v0.w;
    a1.x += s * v1.x; a1.y += s * v1.y; a1.z += s * v1.z; a1.w += s * v1.w;
    a2.x += s * v2.x; a2.y += s * v2.y; a2.z += s * v2.z; a2.w += s * v2.w;
    a3.x += s * v3.x; a3.y += s * v3.y; a3.z += s * v3.z; a3.w += s * v3.w;
  }

  float4* p4 = reinterpret_cast<float4*>(part) +
               (((size_t)(b * CHUNKS + c) * 32 + k) * 32 + fs * 4);
  p4[0] = a0;
  p4[1] = a1;
  p4[2] = a2;
  p4[3] = a3;
}

// ---------------------------------------------------------------------------
// Phase 2b: finalize. Block = (b,k), 128 threads.
// pooled[f] = sum_c part[b][c][k][f]; out = leaky(pooled . lin_w[fo])
// ---------------------------------------------------------------------------
__global__ __launch_bounds__(128) void mempool_out(
    const float* __restrict__ part, const float* __restrict__ lin_w,
    float* __restrict__ out) {
  const int b = blockIdx.x >> 5;
  const int k = blockIdx.x & 31;
  const int t = threadIdx.x;  // 0..127

  __shared__ float pooled[128];
  const float* pp = part + (((size_t)b * CHUNKS) * 32 + k) * 128 + t;
  float pf = 0.f;
#pragma unroll
  for (int c = 0; c < CHUNKS; ++c) pf += pp[(size_t)c * 32 * 128];
  pooled[t] = pf;
  __syncthreads();

  const float4* w4 = reinterpret_cast<const float4*>(lin_w) + t * 32;
  const float4* pl4 = reinterpret_cast<const float4*>(pooled);
  float o = 0.f;
#pragma unroll
  for (int j = 0; j < 32; ++j) {
    const float4 w = w4[j];
    const float4 p = pl4[j];
    o += w.x * p.x + w.y * p.y + w.z * p.z + w.w * p.w;
  }
  o = (o >= 0.f) ? o : 0.01f * o;
  out[(size_t)(b * 32 + k) * 128 + t] = o;
}

// ---------------------------------------------------------------------------
// Fallbacks (no workspace): round-1 structure (known-good).
// ---------------------------------------------------------------------------
__global__ __launch_bounds__(256) void mempool_phase1_fb(
    const float* __restrict__ x, const float* __restrict__ keys,
    const float* __restrict__ conv_w, float* __restrict__ S_out) {
  const int t = threadIdx.x;
  const int hk = t & 127;
  const int half = t >> 7;

  const float4* kq = reinterpret_cast<const float4*>(keys) + hk * 32 + half * 16;
  const float cw = conv_w[(t >> 5) & 3];

  __shared__ float lds_half[128];
  __shared__ float lds_ws[128];

  const int base = blockIdx.x * 8;
  for (int p = 0; p < 8; ++p) {
    const int bn = base + p;
    const float4* xq = reinterpret_cast<const float4*>(x) + bn * 32 + half * 16;
    float a0 = 0.f;
#pragma unroll
    for (int j = 0; j < 16; ++j) {
      const float4 kv = kq[j];
      const float4 xv = xq[j];
      a0 += fabsf(kv.x - xv.x) + fabsf(kv.y - xv.y) + fabsf(kv.z - xv.z) +
            fabsf(kv.w - xv.w);
    }
    if (t >= 128) lds_half[hk] = a0;
    __syncthreads();
    if (t < 128) {
      const float d = a0 + lds_half[hk];
      const float tv = 1.0f / (1.0f + d * d);
      float hs = tv;
#pragma unroll
      for (int m = 1; m < 32; m <<= 1) hs += __shfl_xor(hs, m);
      lds_ws[hk] = cw * tv / hs;
    }
    __syncthreads();
    if (t < 32) {
      float sc = lds_ws[t] + lds_ws[32 + t] + lds_ws[64 + t] + lds_ws[96 + t];
      float mx = sc;
#pragma unroll
      for (int m = 1; m < 32; m <<= 1) mx = fmaxf(mx, __shfl_xor(mx, m));
      const float e = __expf(sc - mx);
      float se = e;
#pragma unroll
      for (int m = 1; m < 32; m <<= 1) se += __shfl_xor(se, m);
      S_out[bn * 32 + t] = e / se;
    }
    __syncthreads();
  }
}

__global__ __launch_bounds__(256) void mempool_phase2_fb(
    const float* __restrict__ x, const float* __restrict__ S,
    const float* __restrict__ lin_w, float* __restrict__ out) {
  const int b = blockIdx.x >> 5;
  const int k = blockIdx.x & 31;
  const int t = threadIdx.x;
  const int fq = t & 31;
  const int seg = t >> 5;

  const float4* xq = reinterpret_cast<const float4*>(x) + (size_t)b * 1024 * 32;
  const float* Sb = S + (size_t)b * 1024 * 32 + k;

  float4 acc = {0.f, 0.f, 0.f, 0.f};
  const int n0 = seg * 128;
#pragma unroll 4
  for (int n = n0; n < n0 + 128; ++n) {
    const float sv = Sb[(size_t)n * 32];
    const float4 xv = xq[n * 32 + fq];
    acc.x += sv * xv.x;
    acc.y += sv * xv.y;
    acc.z += sv * xv.z;
    acc.w += sv * xv.w;
  }

  __shared__ float4 red[8][32];
  red[seg][fq] = acc;
  __syncthreads();

  __shared__ float4 pooled4[32];
  if (t < 32) {
    float4 a = red[0][t];
#pragma unroll
    for (int ss = 1; ss < 8; ++ss) {
      const float4 r = red[ss][t];
      a.x += r.x; a.y += r.y; a.z += r.z; a.w += r.w;
    }
    pooled4[t] = a;
  }
  __syncthreads();

  if (t < 128) {
    const float4* wq = reinterpret_cast<const float4*>(lin_w) + t * 32;
    float o = 0.f;
#pragma unroll
    for (int j = 0; j < 32; ++j) {
      const float4 w = wq[j];
      const float4 p = pooled4[j];
      o += w.x * p.x + w.y * p.y + w.z * p.z + w.w * p.w;
    }
    o = (o >= 0.f) ? o : 0.01f * o;
    out[(size_t)(b * 32 + k) * 128 + t] = o;
  }
}

extern "C" void kernel_launch(void* const* d_in, const int* in_sizes, int n_in,
                              void* d_out, int out_size, void* d_ws, size_t ws_size,
                              hipStream_t stream) {
  const float* x = (const float*)d_in[0];       // [8,1024,128]
  const float* keys = (const float*)d_in[1];    // [4,32,128]
  const float* conv_w = (const float*)d_in[2];  // [4]
  const float* lin_w = (const float*)d_in[3];   // [128,128]

  float* out = (float*)d_out;            // [8,32,128]
  float* S_out = (float*)d_out + 32768;  // [8,1024,32]

  const size_t ktq_floats = 128 * 128;                       // 64 KB
  const size_t part_floats = (size_t)8 * CHUNKS * 32 * 128;  // 4 MB
  const size_t need = (ktq_floats + part_floats) * sizeof(float);

  if (ws_size >= need) {
    float* ktq = (float*)d_ws;
    float* part = (float*)d_ws + ktq_floats;
    mempool_prep<<<16, 256, 0, stream>>>(keys, ktq);
    mempool_phase1<<<8192 / P1_PTS, 256, 0, stream>>>(x, ktq, conv_w, S_out);
    mempool_pool<<<8 * CHUNKS, 256, 0, stream>>>(x, S_out, part);
    mempool_out<<<8 * 32, 128, 0, stream>>>(part, lin_w, out);
  } else {
    mempool_phase1_fb<<<1024, 256, 0, stream>>>(x, keys, conv_w, S_out);
    mempool_phase2_fb<<<8 * 32, 256, 0, stream>>>(x, S_out, lin_w, out);
  }
}

// Round 7
// 32.639 us; speedup vs baseline: 1.3249x; 1.0434x over previous
//
#include <hip/hip_runtime.h>

// Problem constants: B=8, N=1024, F=128, H=4, K=32, TAU=1

// ---------------------------------------------------------------------------
// Prep: transpose keys into KTQ[fq][hk] (float4 = K[hk][4fq..4fq+3]).
// Makes phase-1 key reads coalesced (lane = hk).
// ---------------------------------------------------------------------------
__global__ __launch_bounds__(256) void mempool_prep(
    const float* __restrict__ keys, float* __restrict__ ktq) {
  const int i = blockIdx.x * 256 + threadIdx.x;  // 0..4095
  const int fq = i >> 7;
  const int hk = i & 127;
  reinterpret_cast<float4*>(ktq)[i] =
      reinterpret_cast<const float4*>(keys)[hk * 32 + fq];
}

// ---------------------------------------------------------------------------
// Phase 1: S[bn][k] for all 8192 points.
// 1024 blocks x 256 threads, 8 points/block.
// Thread = (hkp = t&63, q = t>>6): keys {hkp, hkp+64}, f-quarter
// [q*32 .. q*32+32). Each wave owns one f-quarter -> key loads are
// non-duplicated (64 KB/block) and coalesced (1 KB/instr, L2-hot ktq).
// KEY CHANGE vs r6: 2 keys per thread halves the broadcast ds_read count
// (64/thread instead of 128), each read now feeds 16 VALU -> LDS pipe
// (~4.3 us/CU) balanced with VALU floor (~4.3 us/CU) instead of 2x over.
// Epilogue: quarter-combine + Student-t + per-head shfl normalize -> cwsn
// -> conv-combine + softmax over k (32-lane shfl).
// ---------------------------------------------------------------------------
#define P1_PTS 8

__global__ __launch_bounds__(256, 4) void mempool_phase1(
    const float* __restrict__ x, const float* __restrict__ ktq,
    const float* __restrict__ conv_w, float* __restrict__ S_out) {
  const int t = threadIdx.x;
  const int hkp = t & 63;
  const int q = t >> 6;  // f-quarter 0..3

  __shared__ float4 xl[P1_PTS * 32];      // [p][fq], 4 KB
  __shared__ float accs[P1_PTS][4][128];  // [p][q][hk], 16 KB
  __shared__ float cwsn[P1_PTS][4][32];   // [p][h][k], 4 KB

  const int bn0 = blockIdx.x * P1_PTS;

  // Stage x: 256 float4 = 1 per thread, fully coalesced.
  xl[t] = reinterpret_cast<const float4*>(x)[(size_t)bn0 * 32 + t];
  __syncthreads();

  // Key stream base: quads [q*8 .. q*8+8) of rows hkp and hkp+64.
  const float4* kq =
      reinterpret_cast<const float4*>(ktq) + (size_t)(q * 8) * 128 + hkp;

  float acc0[P1_PTS], acc1[P1_PTS];
#pragma unroll
  for (int p = 0; p < P1_PTS; ++p) acc0[p] = acc1[p] = 0.f;

#pragma unroll 4
  for (int j = 0; j < 8; ++j) {
    const float4 kv0 = kq[j * 128];       // coalesced: lanes 0..63 contiguous
    const float4 kv1 = kq[j * 128 + 64];  // second key row
    const int jj = q * 8 + j;
#pragma unroll
    for (int p = 0; p < P1_PTS; ++p) {
      const float4 xv = xl[p * 32 + jj];  // uniform ds_read -> broadcast
      acc0[p] += fabsf(kv0.x - xv.x) + fabsf(kv0.y - xv.y) +
                 fabsf(kv0.z - xv.z) + fabsf(kv0.w - xv.w);
      acc1[p] += fabsf(kv1.x - xv.x) + fabsf(kv1.y - xv.y) +
                 fabsf(kv1.z - xv.z) + fabsf(kv1.w - xv.w);
    }
  }

#pragma unroll
  for (int p = 0; p < P1_PTS; ++p) {
    accs[p][q][hkp] = acc0[p];
    accs[p][q][hkp + 64] = acc1[p];
  }
  __syncthreads();

  // Quarter-combine + Student-t + per-head normalize.
  // 1024 (p,hk) pairs / 256 threads = 4 each; 32-lane groups share (p,h).
  const float4 cwv = *reinterpret_cast<const float4*>(conv_w);
  {
    const int hk = t & 127;
    const float cw = (hk & 64) ? ((hk & 32) ? cwv.w : cwv.z)
                               : ((hk & 32) ? cwv.y : cwv.x);
#pragma unroll
    for (int i = 0; i < 4; ++i) {
      const int p = (t >> 7) + 2 * i;
      const float d = accs[p][0][hk] + accs[p][1][hk] + accs[p][2][hk] +
                      accs[p][3][hk];
      const float tv = __builtin_amdgcn_rcpf(1.f + d * d);  // Student-t
      float hs = tv;
#pragma unroll
      for (int m = 1; m < 32; m <<= 1) hs += __shfl_xor(hs, m);
      cwsn[p][hk >> 5][hk & 31] = cw * tv * __builtin_amdgcn_rcpf(hs);
    }
  }
  __syncthreads();

  // Conv-combine over heads + softmax over k: thread = (p = t>>5, k = t&31).
  {
    const int p = t >> 5;
    const int k = t & 31;
    float sc = cwsn[p][0][k] + cwsn[p][1][k] + cwsn[p][2][k] + cwsn[p][3][k];
    float mx = sc;
#pragma unroll
    for (int m = 1; m < 32; m <<= 1) mx = fmaxf(mx, __shfl_xor(mx, m));
    const float e = __expf(sc - mx);
    float se = e;
#pragma unroll
    for (int m = 1; m < 32; m <<= 1) se += __shfl_xor(se, m);
    S_out[(size_t)(bn0 + p) * 32 + k] = e * __builtin_amdgcn_rcpf(se);
  }
}

// ---------------------------------------------------------------------------
// Phase 2a: partial pooled. Block = (b, chunk c of 32 points); 256 threads =
// (k = t&31, fs = t>>5). x-chunk (16 KB) and S-chunk (4 KB) LDS-staged with
// coalesced loads; inner loop reads are 2-way/broadcast LDS.
// part[b][c][k][f] = sum_{n in chunk} S[b][n][k] * x[b][n][f]
// ---------------------------------------------------------------------------
#define CHUNKS 32
#define CHUNK_N 32

__global__ __launch_bounds__(256) void mempool_pool(
    const float* __restrict__ x, const float* __restrict__ S,
    float* __restrict__ part) {
  const int b = blockIdx.x >> 5;
  const int c = blockIdx.x & 31;
  const int t = threadIdx.x;
  const int k = t & 31;
  const int fs = t >> 5;  // 0..7
  const int n0 = c * CHUNK_N;

  __shared__ float4 xl[CHUNK_N * 32];  // [n][fq], 16 KB
  __shared__ float sl[CHUNK_N * 32];   // [n][k],   4 KB

  {  // stage x: 1024 float4 / 256 thr = 4 each, coalesced
    const float4* xg =
        reinterpret_cast<const float4*>(x) + ((size_t)b * 1024 + n0) * 32;
#pragma unroll
    for (int i = 0; i < 4; ++i) xl[t + i * 256] = xg[t + i * 256];
    // stage S: 1024 floats = 256 float4, coalesced
    reinterpret_cast<float4*>(sl)[t] =
        reinterpret_cast<const float4*>(S + ((size_t)b * 1024 + n0) * 32)[t];
  }
  __syncthreads();

  float4 a0 = {0, 0, 0, 0}, a1 = {0, 0, 0, 0}, a2 = {0, 0, 0, 0},
         a3 = {0, 0, 0, 0};
#pragma unroll 4
  for (int n = 0; n < CHUNK_N; ++n) {
    const float s = sl[n * 32 + k];
    const float4 v0 = xl[n * 32 + fs * 4 + 0];
    const float4 v1 = xl[n * 32 + fs * 4 + 1];
    const float4 v2 = xl[n * 32 + fs * 4 + 2];
    const float4 v3 = xl[n * 32 + fs * 4 + 3];
    a0.x += s * v0.x; a0.y += s * v0.y; a0.z += s * v0.z; a0.w += s * v0.w;
    a1.x += s * v1.x; a1.y += s * v1.y; a1.z += s * v1.z; a1.w += s * v1.w;
    a2.x += s * v2.x; a2.y += s * v2.y; a2.z += s * v2.z; a2.w += s * v2.w;
    a3.x += s * v3.x; a3.y += s * v3.y; a3.z += s * v3.z; a3.w += s * v3.w;
  }

  float4* p4 = reinterpret_cast<float4*>(part) +
               (((size_t)(b * CHUNKS + c) * 32 + k) * 32 + fs * 4);
  p4[0] = a0;
  p4[1] = a1;
  p4[2] = a2;
  p4[3] = a3;
}

// ---------------------------------------------------------------------------
// Phase 2b: finalize. Block = (b,k), 128 threads.
// pooled[f] = sum_c part[b][c][k][f]; out = leaky(pooled . lin_w[fo])
// ---------------------------------------------------------------------------
__global__ __launch_bounds__(128) void mempool_out(
    const float* __restrict__ part, const float* __restrict__ lin_w,
    float* __restrict__ out) {
  const int b = blockIdx.x >> 5;
  const int k = blockIdx.x & 31;
  const int t = threadIdx.x;  // 0..127

  __shared__ float pooled[128];
  const float* pp = part + (((size_t)b * CHUNKS) * 32 + k) * 128 + t;
  float pf = 0.f;
#pragma unroll
  for (int c = 0; c < CHUNKS; ++c) pf += pp[(size_t)c * 32 * 128];
  pooled[t] = pf;
  __syncthreads();

  const float4* w4 = reinterpret_cast<const float4*>(lin_w) + t * 32;
  const float4* pl4 = reinterpret_cast<const float4*>(pooled);
  float o = 0.f;
#pragma unroll
  for (int j = 0; j < 32; ++j) {
    const float4 w = w4[j];
    const float4 p = pl4[j];
    o += w.x * p.x + w.y * p.y + w.z * p.z + w.w * p.w;
  }
  o = (o >= 0.f) ? o : 0.01f * o;
  out[(size_t)(b * 32 + k) * 128 + t] = o;
}

// ---------------------------------------------------------------------------
// Fallbacks (no workspace): round-1 structure (known-good).
// ---------------------------------------------------------------------------
__global__ __launch_bounds__(256) void mempool_phase1_fb(
    const float* __restrict__ x, const float* __restrict__ keys,
    const float* __restrict__ conv_w, float* __restrict__ S_out) {
  const int t = threadIdx.x;
  const int hk = t & 127;
  const int half = t >> 7;

  const float4* kq = reinterpret_cast<const float4*>(keys) + hk * 32 + half * 16;
  const float cw = conv_w[(t >> 5) & 3];

  __shared__ float lds_half[128];
  __shared__ float lds_ws[128];

  const int base = blockIdx.x * 8;
  for (int p = 0; p < 8; ++p) {
    const int bn = base + p;
    const float4* xq = reinterpret_cast<const float4*>(x) + bn * 32 + half * 16;
    float a0 = 0.f;
#pragma unroll
    for (int j = 0; j < 16; ++j) {
      const float4 kv = kq[j];
      const float4 xv = xq[j];
      a0 += fabsf(kv.x - xv.x) + fabsf(kv.y - xv.y) + fabsf(kv.z - xv.z) +
            fabsf(kv.w - xv.w);
    }
    if (t >= 128) lds_half[hk] = a0;
    __syncthreads();
    if (t < 128) {
      const float d = a0 + lds_half[hk];
      const float tv = 1.0f / (1.0f + d * d);
      float hs = tv;
#pragma unroll
      for (int m = 1; m < 32; m <<= 1) hs += __shfl_xor(hs, m);
      lds_ws[hk] = cw * tv / hs;
    }
    __syncthreads();
    if (t < 32) {
      float sc = lds_ws[t] + lds_ws[32 + t] + lds_ws[64 + t] + lds_ws[96 + t];
      float mx = sc;
#pragma unroll
      for (int m = 1; m < 32; m <<= 1) mx = fmaxf(mx, __shfl_xor(mx, m));
      const float e = __expf(sc - mx);
      float se = e;
#pragma unroll
      for (int m = 1; m < 32; m <<= 1) se += __shfl_xor(se, m);
      S_out[bn * 32 + t] = e / se;
    }
    __syncthreads();
  }
}

__global__ __launch_bounds__(256) void mempool_phase2_fb(
    const float* __restrict__ x, const float* __restrict__ S,
    const float* __restrict__ lin_w, float* __restrict__ out) {
  const int b = blockIdx.x >> 5;
  const int k = blockIdx.x & 31;
  const int t = threadIdx.x;
  const int fq = t & 31;
  const int seg = t >> 5;

  const float4* xq = reinterpret_cast<const float4*>(x) + (size_t)b * 1024 * 32;
  const float* Sb = S + (size_t)b * 1024 * 32 + k;

  float4 acc = {0.f, 0.f, 0.f, 0.f};
  const int n0 = seg * 128;
#pragma unroll 4
  for (int n = n0; n < n0 + 128; ++n) {
    const float sv = Sb[(size_t)n * 32];
    const float4 xv = xq[n * 32 + fq];
    acc.x += sv * xv.x;
    acc.y += sv * xv.y;
    acc.z += sv * xv.z;
    acc.w += sv * xv.w;
  }

  __shared__ float4 red[8][32];
  red[seg][fq] = acc;
  __syncthreads();

  __shared__ float4 pooled4[32];
  if (t < 32) {
    float4 a = red[0][t];
#pragma unroll
    for (int ss = 1; ss < 8; ++ss) {
      const float4 r = red[ss][t];
      a.x += r.x; a.y += r.y; a.z += r.z; a.w += r.w;
    }
    pooled4[t] = a;
  }
  __syncthreads();

  if (t < 128) {
    const float4* wq = reinterpret_cast<const float4*>(lin_w) + t * 32;
    float o = 0.f;
#pragma unroll
    for (int j = 0; j < 32; ++j) {
      const float4 w = wq[j];
      const float4 p = pooled4[j];
      o += w.x * p.x + w.y * p.y + w.z * p.z + w.w * p.w;
    }
    o = (o >= 0.f) ? o : 0.01f * o;
    out[(size_t)(b * 32 + k) * 128 + t] = o;
  }
}

extern "C" void kernel_launch(void* const* d_in, const int* in_sizes, int n_in,
                              void* d_out, int out_size, void* d_ws, size_t ws_size,
                              hipStream_t stream) {
  const float* x = (const float*)d_in[0];       // [8,1024,128]
  const float* keys = (const float*)d_in[1];    // [4,32,128]
  const float* conv_w = (const float*)d_in[2];  // [4]
  const float* lin_w = (const float*)d_in[3];   // [128,128]

  float* out = (float*)d_out;            // [8,32,128]
  float* S_out = (float*)d_out + 32768;  // [8,1024,32]

  const size_t ktq_floats = 128 * 128;                       // 64 KB
  const size_t part_floats = (size_t)8 * CHUNKS * 32 * 128;  // 4 MB
  const size_t need = (ktq_floats + part_floats) * sizeof(float);

  if (ws_size >= need) {
    float* ktq = (float*)d_ws;
    float* part = (float*)d_ws + ktq_floats;
    mempool_prep<<<16, 256, 0, stream>>>(keys, ktq);
    mempool_phase1<<<8192 / P1_PTS, 256, 0, stream>>>(x, ktq, conv_w, S_out);
    mempool_pool<<<8 * CHUNKS, 256, 0, stream>>>(x, S_out, part);
    mempool_out<<<8 * 32, 128, 0, stream>>>(part, lin_w, out);
  } else {
    mempool_phase1_fb<<<1024, 256, 0, stream>>>(x, keys, conv_w, S_out);
    mempool_phase2_fb<<<8 * 32, 256, 0, stream>>>(x, S_out, lin_w, out);
  }
}

// Round 8
// 26.193 us; speedup vs baseline: 1.6510x; 1.2461x over previous
//
#include <hip/hip_runtime.h>

// Problem constants: B=8, N=1024, F=128, H=4, K=32, TAU=1
typedef unsigned int uint32;
typedef unsigned short ushort16;

#define P1_PTS 16      // points per A-block
#define P1_BLOCKS 512  // 8192 / P1_PTS
#define NCHUNK_B 64    // chunks per batch = 1024 / P1_PTS

// round-to-nearest-even f32 -> bf16 bits
static __device__ __forceinline__ ushort16 f2bf(float f) {
  uint32 u = __float_as_uint(f);
  return (ushort16)((u + 0x7FFFu + ((u >> 16) & 1u)) >> 16);
}

// ---------------------------------------------------------------------------
// Prep: transpose keys into KTQ[fq][hk] (float4 = K[hk][4fq..4fq+3]).
// ---------------------------------------------------------------------------
__global__ __launch_bounds__(256) void mempool_prep(
    const float* __restrict__ keys, float* __restrict__ ktq) {
  const int i = blockIdx.x * 256 + threadIdx.x;  // 0..4095
  const int fq = i >> 7;
  const int hk = i & 127;
  reinterpret_cast<float4*>(ktq)[i] =
      reinterpret_cast<const float4*>(keys)[hk * 32 + fq];
}

// ---------------------------------------------------------------------------
// Fused A: per block of 16 points: distances -> Student-t -> per-head
// normalize -> conv-combine -> softmax (S written to S_out + LDS), THEN the
// partial pooled contribution of these 16 points (bf16) -> part[block][k][f].
// 512 blocks x 256 threads. Thread = (hkp = t&63, q = t>>6): keys
// {hkp, hkp+64}, f-quarter q (wave-owned -> key VMEM non-duplicated,
// coalesced 1 KB/instr from L2-hot ktq). x reads are broadcast ds_reads.
// ---------------------------------------------------------------------------
__global__ __launch_bounds__(256, 2) void mempool_A(
    const float* __restrict__ x, const float* __restrict__ ktq,
    const float* __restrict__ conv_w, float* __restrict__ S_out,
    ushort16* __restrict__ part) {
  const int t = threadIdx.x;
  const int hkp = t & 63;
  const int q = t >> 6;  // f-quarter 0..3

  __shared__ float4 xl[P1_PTS * 32];        // [p][fq], 8 KB
  __shared__ float accs[P1_PTS][4][128];    // [p][q][hk], 32 KB
  __shared__ float cwsn[P1_PTS][4][32];     // [p][h][k], 8 KB
  __shared__ float sl[P1_PTS][32];          // [p][k], 2 KB

  const int bn0 = blockIdx.x * P1_PTS;

  // Stage x: 512 float4 = 2 per thread, fully coalesced.
  {
    const float4* xg = reinterpret_cast<const float4*>(x) + (size_t)bn0 * 32;
    xl[t] = xg[t];
    xl[t + 256] = xg[t + 256];
  }
  __syncthreads();

  // Key stream: quads [q*8 .. q*8+8) of rows hkp and hkp+64.
  const float4* kq =
      reinterpret_cast<const float4*>(ktq) + (size_t)(q * 8) * 128 + hkp;

  float acc0[P1_PTS], acc1[P1_PTS];
#pragma unroll
  for (int p = 0; p < P1_PTS; ++p) acc0[p] = acc1[p] = 0.f;

#pragma unroll
  for (int j = 0; j < 8; ++j) {
    const float4 kv0 = kq[j * 128];       // coalesced (lanes 0..63 contiguous)
    const float4 kv1 = kq[j * 128 + 64];  // second key row
    const int jj = q * 8 + j;
#pragma unroll
    for (int p = 0; p < P1_PTS; ++p) {
      const float4 xv = xl[p * 32 + jj];  // uniform ds_read -> broadcast
      acc0[p] += fabsf(kv0.x - xv.x) + fabsf(kv0.y - xv.y) +
                 fabsf(kv0.z - xv.z) + fabsf(kv0.w - xv.w);
      acc1[p] += fabsf(kv1.x - xv.x) + fabsf(kv1.y - xv.y) +
                 fabsf(kv1.z - xv.z) + fabsf(kv1.w - xv.w);
    }
  }

#pragma unroll
  for (int p = 0; p < P1_PTS; ++p) {
    accs[p][q][hkp] = acc0[p];
    accs[p][q][hkp + 64] = acc1[p];
  }
  __syncthreads();

  // Quarter-combine + Student-t + per-head normalize.
  // 2048 (p,hk) cells / 256 threads = 8 each; 32-lane groups share (p,h).
  const float4 cwv = *reinterpret_cast<const float4*>(conv_w);
  {
    const int hk = t & 127;
    const float cw = (hk & 64) ? ((hk & 32) ? cwv.w : cwv.z)
                               : ((hk & 32) ? cwv.y : cwv.x);
#pragma unroll
    for (int i = 0; i < 8; ++i) {
      const int p = (t >> 7) + 2 * i;
      const float d = accs[p][0][hk] + accs[p][1][hk] + accs[p][2][hk] +
                      accs[p][3][hk];
      const float tv = __builtin_amdgcn_rcpf(1.f + d * d);  // Student-t, tau=1
      float hs = tv;
#pragma unroll
      for (int m = 1; m < 32; m <<= 1) hs += __shfl_xor(hs, m);
      cwsn[p][hk >> 5][hk & 31] = cw * tv * __builtin_amdgcn_rcpf(hs);
    }
  }
  __syncthreads();

  // Conv-combine over heads + softmax over k. 16 p x 32 k = 2 passes.
#pragma unroll
  for (int pp = 0; pp < 2; ++pp) {
    const int p = pp * 8 + (t >> 5);
    const int k = t & 31;
    float sc = cwsn[p][0][k] + cwsn[p][1][k] + cwsn[p][2][k] + cwsn[p][3][k];
    float mx = sc;
#pragma unroll
    for (int m = 1; m < 32; m <<= 1) mx = fmaxf(mx, __shfl_xor(mx, m));
    const float e = __expf(sc - mx);
    float se = e;
#pragma unroll
    for (int m = 1; m < 32; m <<= 1) se += __shfl_xor(se, m);
    const float sv = e * __builtin_amdgcn_rcpf(se);
    S_out[(size_t)(bn0 + p) * 32 + k] = sv;
    sl[p][k] = sv;
  }
  __syncthreads();

  // Partial pooled: thread = (k = t&31, fs = t>>5; f in [fs*16, fs*16+16)).
  // part[blk][k][f] = sum_{p} sl[p][k] * xl[p][f], bf16.
  {
    const int k = t & 31;
    const int fs = t >> 5;
    float4 a0 = {0, 0, 0, 0}, a1 = {0, 0, 0, 0}, a2 = {0, 0, 0, 0},
           a3 = {0, 0, 0, 0};
#pragma unroll
    for (int p = 0; p < P1_PTS; ++p) {
      const float s = sl[p][k];  // 32 distinct -> conflict-free
      const float4 v0 = xl[p * 32 + fs * 4 + 0];  // broadcast per 32-group
      const float4 v1 = xl[p * 32 + fs * 4 + 1];
      const float4 v2 = xl[p * 32 + fs * 4 + 2];
      const float4 v3 = xl[p * 32 + fs * 4 + 3];
      a0.x += s * v0.x; a0.y += s * v0.y; a0.z += s * v0.z; a0.w += s * v0.w;
      a1.x += s * v1.x; a1.y += s * v1.y; a1.z += s * v1.z; a1.w += s * v1.w;
      a2.x += s * v2.x; a2.y += s * v2.y; a2.z += s * v2.z; a2.w += s * v2.w;
      a3.x += s * v3.x; a3.y += s * v3.y; a3.z += s * v3.z; a3.w += s * v3.w;
    }
    uint32 w0 = f2bf(a0.x) | ((uint32)f2bf(a0.y) << 16);
    uint32 w1 = f2bf(a0.z) | ((uint32)f2bf(a0.w) << 16);
    uint32 w2 = f2bf(a1.x) | ((uint32)f2bf(a1.y) << 16);
    uint32 w3 = f2bf(a1.z) | ((uint32)f2bf(a1.w) << 16);
    uint32 w4 = f2bf(a2.x) | ((uint32)f2bf(a2.y) << 16);
    uint32 w5 = f2bf(a2.z) | ((uint32)f2bf(a2.w) << 16);
    uint32 w6 = f2bf(a3.x) | ((uint32)f2bf(a3.y) << 16);
    uint32 w7 = f2bf(a3.z) | ((uint32)f2bf(a3.w) << 16);
    uint4* dst = reinterpret_cast<uint4*>(
        part + (((size_t)blockIdx.x * 32 + k) * 128 + fs * 16));
    dst[0] = make_uint4(w0, w1, w2, w3);
    dst[1] = make_uint4(w4, w5, w6, w7);
  }
}

// ---------------------------------------------------------------------------
// Out: block = (b,k), 256 threads.
// pooled[f] = sum_{c=0..64} part[b*64+c][k][f] (bf16->f32), then
// out[b][k][fo] = leakyrelu(pooled . lin_w[fo]).
// Reduce layout: thread = (f2 = t&63 -> features 2f2,2f2+1; ch = t>>6 ->
// 16 chunks each). Coalesced 256 B uint loads per chunk step.
// ---------------------------------------------------------------------------
__global__ __launch_bounds__(256) void mempool_out(
    const ushort16* __restrict__ part, const float* __restrict__ lin_w,
    float* __restrict__ out) {
  const int b = blockIdx.x >> 5;
  const int k = blockIdx.x & 31;
  const int t = threadIdx.x;
  const int f2 = t & 63;
  const int ch = t >> 6;  // 0..3

  __shared__ float red[4][128];
  __shared__ float pooled[128];

  float sx = 0.f, sy = 0.f;
  // uint index: ((cg*32 + k)*128 + 2*f2) / 2 = (cg*32 + k)*64 + f2
  const uint32* pp = reinterpret_cast<const uint32*>(part) +
                     ((size_t)((b * NCHUNK_B + ch * 16) * 32 + k)) * 64 + f2;
#pragma unroll
  for (int cc = 0; cc < 16; ++cc) {
    const uint32 v = pp[(size_t)cc * 32 * 64];
    sx += __uint_as_float(v << 16);
    sy += __uint_as_float(v & 0xFFFF0000u);
  }
  red[ch][f2 * 2] = sx;
  red[ch][f2 * 2 + 1] = sy;
  __syncthreads();

  if (t < 128) pooled[t] = red[0][t] + red[1][t] + red[2][t] + red[3][t];
  __syncthreads();

  if (t < 128) {
    const float4* w4 = reinterpret_cast<const float4*>(lin_w) + t * 32;
    const float4* pl4 = reinterpret_cast<const float4*>(pooled);
    float o = 0.f;
#pragma unroll
    for (int j = 0; j < 32; ++j) {
      const float4 w = w4[j];
      const float4 p = pl4[j];
      o += w.x * p.x + w.y * p.y + w.z * p.z + w.w * p.w;
    }
    o = (o >= 0.f) ? o : 0.01f * o;
    out[(size_t)(b * 32 + k) * 128 + t] = o;
  }
}

// ---------------------------------------------------------------------------
// Fallbacks (no workspace): round-1 structure (known-good).
// ---------------------------------------------------------------------------
__global__ __launch_bounds__(256) void mempool_phase1_fb(
    const float* __restrict__ x, const float* __restrict__ keys,
    const float* __restrict__ conv_w, float* __restrict__ S_out) {
  const int t = threadIdx.x;
  const int hk = t & 127;
  const int half = t >> 7;

  const float4* kq = reinterpret_cast<const float4*>(keys) + hk * 32 + half * 16;
  const float cw = conv_w[(t >> 5) & 3];

  __shared__ float lds_half[128];
  __shared__ float lds_ws[128];

  const int base = blockIdx.x * 8;
  for (int p = 0; p < 8; ++p) {
    const int bn = base + p;
    const float4* xq = reinterpret_cast<const float4*>(x) + bn * 32 + half * 16;
    float a0 = 0.f;
#pragma unroll
    for (int j = 0; j < 16; ++j) {
      const float4 kv = kq[j];
      const float4 xv = xq[j];
      a0 += fabsf(kv.x - xv.x) + fabsf(kv.y - xv.y) + fabsf(kv.z - xv.z) +
            fabsf(kv.w - xv.w);
    }
    if (t >= 128) lds_half[hk] = a0;
    __syncthreads();
    if (t < 128) {
      const float d = a0 + lds_half[hk];
      const float tv = 1.0f / (1.0f + d * d);
      float hs = tv;
#pragma unroll
      for (int m = 1; m < 32; m <<= 1) hs += __shfl_xor(hs, m);
      lds_ws[hk] = cw * tv / hs;
    }
    __syncthreads();
    if (t < 32) {
      float sc = lds_ws[t] + lds_ws[32 + t] + lds_ws[64 + t] + lds_ws[96 + t];
      float mx = sc;
#pragma unroll
      for (int m = 1; m < 32; m <<= 1) mx = fmaxf(mx, __shfl_xor(mx, m));
      const float e = __expf(sc - mx);
      float se = e;
#pragma unroll
      for (int m = 1; m < 32; m <<= 1) se += __shfl_xor(se, m);
      S_out[bn * 32 + t] = e / se;
    }
    __syncthreads();
  }
}

__global__ __launch_bounds__(256) void mempool_phase2_fb(
    const float* __restrict__ x, const float* __restrict__ S,
    const float* __restrict__ lin_w, float* __restrict__ out) {
  const int b = blockIdx.x >> 5;
  const int k = blockIdx.x & 31;
  const int t = threadIdx.x;
  const int fq = t & 31;
  const int seg = t >> 5;

  const float4* xq = reinterpret_cast<const float4*>(x) + (size_t)b * 1024 * 32;
  const float* Sb = S + (size_t)b * 1024 * 32 + k;

  float4 acc = {0.f, 0.f, 0.f, 0.f};
  const int n0 = seg * 128;
#pragma unroll 4
  for (int n = n0; n < n0 + 128; ++n) {
    const float sv = Sb[(size_t)n * 32];
    const float4 xv = xq[n * 32 + fq];
    acc.x += sv * xv.x;
    acc.y += sv * xv.y;
    acc.z += sv * xv.z;
    acc.w += sv * xv.w;
  }

  __shared__ float4 red[8][32];
  red[seg][fq] = acc;
  __syncthreads();

  __shared__ float4 pooled4[32];
  if (t < 32) {
    float4 a = red[0][t];
#pragma unroll
    for (int ss = 1; ss < 8; ++ss) {
      const float4 r = red[ss][t];
      a.x += r.x; a.y += r.y; a.z += r.z; a.w += r.w;
    }
    pooled4[t] = a;
  }
  __syncthreads();

  if (t < 128) {
    const float4* wq = reinterpret_cast<const float4*>(lin_w) + t * 32;
    float o = 0.f;
#pragma unroll
    for (int j = 0; j < 32; ++j) {
      const float4 w = wq[j];
      const float4 p = pooled4[j];
      o += w.x * p.x + w.y * p.y + w.z * p.z + w.w * p.w;
    }
    o = (o >= 0.f) ? o : 0.01f * o;
    out[(size_t)(b * 32 + k) * 128 + t] = o;
  }
}

extern "C" void kernel_launch(void* const* d_in, const int* in_sizes, int n_in,
                              void* d_out, int out_size, void* d_ws, size_t ws_size,
                              hipStream_t stream) {
  const float* x = (const float*)d_in[0];       // [8,1024,128]
  const float* keys = (const float*)d_in[1];    // [4,32,128]
  const float* conv_w = (const float*)d_in[2];  // [4]
  const float* lin_w = (const float*)d_in[3];   // [128,128]

  float* out = (float*)d_out;            // [8,32,128]
  float* S_out = (float*)d_out + 32768;  // [8,1024,32]

  const size_t ktq_bytes = 128 * 128 * sizeof(float);                // 64 KB
  const size_t part_bytes = (size_t)P1_BLOCKS * 32 * 128 * 2;        // 4 MB
  const size_t need = ktq_bytes + part_bytes;

  if (ws_size >= need) {
    float* ktq = (float*)d_ws;
    ushort16* part = (ushort16*)((char*)d_ws + ktq_bytes);
    mempool_prep<<<16, 256, 0, stream>>>(keys, ktq);
    mempool_A<<<P1_BLOCKS, 256, 0, stream>>>(x, ktq, conv_w, S_out, part);
    mempool_out<<<8 * 32, 256, 0, stream>>>(part, lin_w, out);
  } else {
    mempool_phase1_fb<<<1024, 256, 0, stream>>>(x, keys, conv_w, S_out);
    mempool_phase2_fb<<<8 * 32, 256, 0, stream>>>(x, S_out, lin_w, out);
  }
}